// Round 12
// baseline (289.233 us; speedup 1.0000x reference)
//
#include <hip/hip_runtime.h>
#include <stdint.h>

#define HW 9216
#define CDIM 128
#define WIDTH 96
#define BATCH 2
#define SPLITS 48           // 48 key-splits -> 48 partial streams
#define KSPLIT 192          // keys per split; LDS 48 KB -> 3 blocks/CU
#define NKG 6               // 192 / 32 keys per key-group
#define QTILE 128           // q-rows per block (4 waves x 32q)
#define NQT (HW / QTILE)    // 72 q-tiles
#define NWG (NQT * SPLITS * BATCH)   // 6912 blocks = 8 x 864

// log2(e)/(0.1*sqrt(128)): logits in log2 domain, e = exp2(w). |w| <= 1.276.
#define QSCALE 1.2753324954171245f

typedef _Float16 half8 __attribute__((ext_vector_type(8)));
typedef _Float16 half2v __attribute__((ext_vector_type(2)));
typedef float f32x16 __attribute__((ext_vector_type(16)));
typedef uint32_t u32x4 __attribute__((ext_vector_type(4)));

// ---------------------------------------------------------------------------
// Kernel 1: L2-normalize over C, write fp16 [B][HW][C] (unchanged).
// ---------------------------------------------------------------------------
__global__ __launch_bounds__(256) void norm_kernel(const float* __restrict__ fL,
                                                   const float* __restrict__ fR,
                                                   _Float16* __restrict__ Qh,
                                                   _Float16* __restrict__ Kh)
{
    __shared__ float ssred[4][64];
    __shared__ _Float16 ot[64 * 130];   // +2 halves pad -> bank advance 1/row

    const float* src = (blockIdx.y == 0) ? fL : fR;
    _Float16* dst    = (blockIdx.y == 0) ? Qh : Kh;
    const float outScale = (blockIdx.y == 0) ? QSCALE : 1.0f;

    const int t = threadIdx.x;
    const int pos_l = t & 63, cg = t >> 6;            // 4 channel groups of 32
    const int pos0 = blockIdx.x * 64;                  // 64 | HW so no straddle
    const int b = pos0 / HW, pos_in = pos0 % HW + pos_l;

    const float* p = src + (size_t)b * CDIM * HW + pos_in;

    float v[32];
    float ss = 0.f;
    #pragma unroll
    for (int j = 0; j < 32; ++j) {
        v[j] = p[(size_t)(cg * 32 + j) * HW];
        ss += v[j] * v[j];
    }
    ssred[cg][pos_l] = ss;
    __syncthreads();
    float tot = ssred[0][pos_l] + ssred[1][pos_l] + ssred[2][pos_l] + ssred[3][pos_l];
    float scale = outScale / fmaxf(sqrtf(tot), 1e-6f);

    #pragma unroll
    for (int j = 0; j < 32; ++j)
        ot[pos_l * 130 + cg * 32 + j] = (_Float16)(v[j] * scale);
    __syncthreads();

    uint4* og = (uint4*)(dst + (size_t)(b * HW + pos0 % HW + 0) * CDIM);
    #pragma unroll
    for (int i = 0; i < 4; ++i) {
        int idx = i * 256 + t;            // 0..1023 dwordx4 slots
        int row = idx >> 4, chunk = idx & 15;
        og[idx] = *(const uint4*)&ot[row * 130 + chunk * 8];
    }
}

// ---------------------------------------------------------------------------
// Kernel 2: correlation + softmax-accumulate with PV-MFMA reduction.
//   9 structural experiments (r0-r11) left one invariant: the per-logit
//   VALU epilogue (~520 cy/kg scalarized; VALUBusy 50% = 38 us). This round
//   DELETES it: l/ax/ay are dot-products of e with key-constants -> done by
//   2 extra MFMAs per kg against a constant V (col0=1 -> l, col1=x -> ax,
//   col2=y -> ay), accumulated in ONE f32x16 across all 6 kgs.
//   Per-kg VALU now: 16 bare v_exp_f32 (log2-domain logits, r0 scaling),
//   8 max3, 8 cvt_pkrtz (e->f16), 8 shfl_xor(32) + 8 selects to assemble
//   P-fragments (lane=q needs keys 0..15 / 16..31; half live in partner
//   hi-lanes). Final (l,ax,ay): one 1.5 KB LDS transpose of the PV acc
//   (D: col=lane31, row q' = (r&3)+8*(r>>2)+4*hi  [m74/m101 layout]).
//   Geometry r9-proven: KSPLIT 192, 48 KB Ks staged once, 3 blocks/CU,
//   2-acc ping-pong CHAIN/EPI, XCD-chunked qt-fastest.
//   Checks: VGPR ~140-155 & WRITE_SIZE 13.8 MB (no spill); absmax may rise
//   slightly (f16 P) but << 0.95.
// ---------------------------------------------------------------------------
__global__ __launch_bounds__(256, 3) void attn_kernel(const _Float16* __restrict__ Qh,
                                                      const _Float16* __restrict__ Kh,
                                                      float4* __restrict__ part)
{
    __shared__ __align__(16) _Float16 Ks[KSPLIT * 128];   // 48 KB, staged once
    __shared__ float tr[4][3][32];                        // PV transpose, 1.5 KB

    const int wg0 = blockIdx.x;
    const int nid = (wg0 & 7) * (NWG / 8) + (wg0 >> 3);
    const int qt = nid % NQT;
    const int sb = nid / NQT;                  // 0..95
    const int split = sb % SPLITS;
    const int b = sb / SPLITS;

    const int t = threadIdx.x;
    const int lane = t & 63, wave = t >> 6;        // 4 waves
    const int lane31 = lane & 31, hi = lane >> 5;
    const int ln15 = lane & 15, qd = lane >> 4;

    const char* kp0 = (const char*)(Kh + (size_t)b * HW * CDIM) +
                      (size_t)(split * KSPLIT) * (CDIM * 2);

    // ---- stage the whole K-split: wave stages rows [wave*48, wave*48+48) ----
    {
        int voff4[4];
        #pragma unroll
        for (int i = 0; i < 4; ++i) {
            int r = wave * 48 + i * 4 + qd;
            voff4[i] = r * 256 + ((ln15 ^ (r & 15)) << 4) - i * 1024;
        }
        _Float16* db = &Ks[wave * (48 * 128)];
        #pragma unroll
        for (int i = 0; i < 12; ++i)
            __builtin_amdgcn_global_load_lds(
                (const __attribute__((address_space(1))) uint32_t*)(kp0 + voff4[i & 3] + i * 1024),
                (__attribute__((address_space(3))) uint32_t*)(db + i * 512),
                16, 0, 0);
    }

    // ---- Q fragments (B-operand of QK): col = lane31 = q-row, k = hi*8+j ----
    half8 qf[8];
    {
        const char* qb = (const char*)(Qh +
            ((size_t)(b * HW + qt * QTILE + wave * 32 + lane31)) * CDIM);
        #pragma unroll
        for (int kc = 0; kc < 8; ++kc)
            qf[kc] = *(const half8*)(qb + kc * 32 + hi * 16);
    }

    // K-frag (A-operand) LDS byte offsets: row = lane31, chunk (kc*2+hi)^ln15
    int rdoff[8];
    #pragma unroll
    for (int kc = 0; kc < 8; ++kc)
        rdoff[kc] = (lane31 << 8) + ((((kc << 1) | hi) ^ ln15) << 4);

    // ---- V-matrix fragments for PV (B-operand): per phase ph (xb = 32*ph),
    // per 16-key half m. B[k=hi*8+j][col=lane31]: col0 = 1, col1 = x =
    // 32*ph + m*16 + k, col2 = y = split*2 (+1 bumped at kg>=3), else 0.
    const float ysp = (float)(split * 2);
    half8 Bv[3][2];
    {
        const int col = lane31;
        const uint32_t onepk = 0x3C003C00u;
        uint32_t ypk = __builtin_bit_cast(uint32_t,
                           __builtin_amdgcn_cvt_pkrtz(ysp, ysp));
        #pragma unroll
        for (int ph = 0; ph < 3; ++ph)
            #pragma unroll
            for (int m = 0; m < 2; ++m) {
                u32x4 bb;
                #pragma unroll
                for (int jj = 0; jj < 4; ++jj) {
                    float x0 = (float)(32 * ph + m * 16 + hi * 8 + 2 * jj);
                    uint32_t xpk = __builtin_bit_cast(uint32_t,
                                       __builtin_amdgcn_cvt_pkrtz(x0, x0 + 1.f));
                    bb[jj] = (col == 0) ? onepk : (col == 1) ? xpk
                           : (col == 2) ? ypk : 0u;
                }
                Bv[ph][m] = __builtin_bit_cast(half8, bb);
            }
    }

    f32x16 pv = (f32x16)0.f;     // D[row=q'][col]: col0=l, col1=ax, col2=ay
    float mxs = -1.0e30f;

    const char* ksb = (const char*)&Ks[0];

    __syncthreads();   // K fully staged

    #define CHAIN(ACC, KG)                                                       \
        {                                                                        \
            __builtin_amdgcn_s_setprio(1);                                       \
            _Pragma("unroll")                                                    \
            for (int kc = 0; kc < 8; ++kc) {                                     \
                half8 kf = *(const half8*)(ksb + (KG) * 8192 + rdoff[kc]);       \
                ACC = __builtin_amdgcn_mfma_f32_32x32x16_f16(                    \
                    kf, qf[kc], (kc == 0) ? (f32x16)0.f : ACC, 0, 0, 0);         \
            }                                                                    \
            __builtin_amdgcn_s_setprio(0);                                       \
        }

    // EPI: exp2 + max + f16-pack + cross-hi exchange + 2 PV MFMAs.
    // Lane holds P[keys (2p pairs)+4hi][q=lane31]; A-frag needs keys m*16 +
    // hi*8+j: the other half lives in the partner hi-lane -> shfl_xor(32).
    #define EPI(ACC, PH)                                                         \
        {                                                                        \
            uint32_t ep[8], sw[8];                                               \
            _Pragma("unroll")                                                    \
            for (int p = 0; p < 8; ++p) {                                        \
                float wx = ACC[2 * p], wy = ACC[2 * p + 1];                      \
                mxs = fmaxf(mxs, fmaxf(wx, wy));                                 \
                float ex = __builtin_amdgcn_exp2f(wx);                           \
                float ey = __builtin_amdgcn_exp2f(wy);                           \
                ep[p] = __builtin_bit_cast(uint32_t,                             \
                            __builtin_amdgcn_cvt_pkrtz(ex, ey));                 \
            }                                                                    \
            _Pragma("unroll")                                                    \
            for (int p = 0; p < 8; ++p)                                          \
                sw[p] = (uint32_t)__shfl_xor((int)ep[p], 32, 64);                \
            u32x4 a1, a2;                                                        \
            a1[0] = hi ? sw[2] : ep[0]; a1[1] = hi ? sw[3] : ep[1];              \
            a1[2] = hi ? ep[2] : sw[0]; a1[3] = hi ? ep[3] : sw[1];              \
            a2[0] = hi ? sw[6] : ep[4]; a2[1] = hi ? sw[7] : ep[5];              \
            a2[2] = hi ? ep[6] : sw[4]; a2[3] = hi ? ep[7] : sw[5];              \
            pv = __builtin_amdgcn_mfma_f32_32x32x16_f16(                         \
                     __builtin_bit_cast(half8, a1), Bv[PH][0], pv, 0, 0, 0);     \
            pv = __builtin_amdgcn_mfma_f32_32x32x16_f16(                         \
                     __builtin_bit_cast(half8, a2), Bv[PH][1], pv, 0, 0, 0);     \
        }

    f32x16 accA, accB;
    CHAIN(accA, 0)
    CHAIN(accB, 1) __builtin_amdgcn_sched_barrier(0); EPI(accA, 0)
    CHAIN(accA, 2) __builtin_amdgcn_sched_barrier(0); EPI(accB, 1)
    CHAIN(accB, 3) __builtin_amdgcn_sched_barrier(0); EPI(accA, 2)
    {   // y bump: kgs 3-5 have y = ysp + 1; add 1.0 to col==2 lanes' V
        const _Float16 dyv = (lane31 == 2) ? (_Float16)1.0f : (_Float16)0.0f;
        half8 dy8 = { dyv, dyv, dyv, dyv, dyv, dyv, dyv, dyv };
        #pragma unroll
        for (int ph = 0; ph < 3; ++ph)
            #pragma unroll
            for (int m = 0; m < 2; ++m)
                Bv[ph][m] += dy8;
    }
    CHAIN(accA, 4) __builtin_amdgcn_sched_barrier(0); EPI(accB, 0)
    CHAIN(accB, 5) __builtin_amdgcn_sched_barrier(0); EPI(accA, 1)
    EPI(accB, 2)
    #undef CHAIN
    #undef EPI

    // ---- extract: PV D row q' = (r&3)+8*(r>>2)+4*hi, col = lane31 ----
    if (lane31 < 3) {
        #pragma unroll
        for (int r = 0; r < 16; ++r) {
            int qp = (r & 3) + 8 * (r >> 2) + 4 * hi;
            tr[wave][lane31][qp] = pv[r];
        }
    }
    float mx = fmaxf(mxs, __shfl_xor(mxs, 32, 64));   // both hi key-halves
    __syncthreads();

    if (hi == 0) {
        float l  = tr[wave][0][lane31];
        float ax = tr[wave][1][lane31];
        float ay = tr[wave][2][lane31];
        int row = qt * QTILE + wave * 32 + lane31;
        part[(size_t)split * (BATCH * HW) + b * HW + row] =
            make_float4(l, ax, ay, __builtin_amdgcn_exp2f(mx));
    }
}

// ---------------------------------------------------------------------------
// Kernel 3: combine 48 partials per query row — 288 blocks, LDS tree-reduce.
// ---------------------------------------------------------------------------
__global__ __launch_bounds__(256) void combine_kernel(const float4* __restrict__ part,
                                                      float* __restrict__ out)
{
    __shared__ float4 red[3][64];
    const int t = threadIdx.x;
    const int r = t & 63, g = t >> 6;            // row-in-block, split-group
    const int tid = blockIdx.x * 64 + r;         // 0 .. B*HW-1 (288 blocks)
    const int b = tid / HW, pos = tid % HW;

    float l = 0.f, ax = 0.f, ay = 0.f, mx = 0.f;
    #pragma unroll
    for (int s = 0; s < 12; ++s) {
        float4 v = part[(size_t)(g * 12 + s) * (BATCH * HW) + tid];
        l += v.x; ax += v.y; ay += v.z; mx = fmaxf(mx, v.w);
    }
    if (g > 0) red[g - 1][r] = make_float4(l, ax, ay, mx);
    __syncthreads();
    if (g == 0) {
        #pragma unroll
        for (int i = 0; i < 3; ++i) {
            float4 v = red[i][r];
            l += v.x; ax += v.y; ay += v.z; mx = fmaxf(mx, v.w);
        }
        float inv = 1.0f / l;
        int x = pos % WIDTH, y = pos / WIDTH;
        out[(size_t)b * 2 * HW + pos]                      = ax * inv - (float)x;
        out[(size_t)b * 2 * HW + HW + pos]                 = ay * inv - (float)y;
        out[(size_t)BATCH * 2 * HW + (size_t)b * HW + pos] = mx * inv;
    }
}

// ---------------------------------------------------------------------------
extern "C" void kernel_launch(void* const* d_in, const int* in_sizes, int n_in,
                              void* d_out, int out_size, void* d_ws, size_t ws_size,
                              hipStream_t stream)
{
    const float* fL = (const float*)d_in[0];
    const float* fR = (const float*)d_in[1];
    float* out = (float*)d_out;

    char* ws = (char*)d_ws;
    const size_t QH_BYTES = (size_t)BATCH * HW * CDIM * sizeof(_Float16);  // 4.72 MB
    _Float16* Qh  = (_Float16*)ws;
    _Float16* Kh  = (_Float16*)(ws + QH_BYTES);
    float4*   part = (float4*)(ws + 2 * QH_BYTES);                         // 14.16 MB

    norm_kernel<<<dim3((BATCH * HW) / 64, 2), 256, 0, stream>>>(fL, fR, Qh, Kh);
    attn_kernel<<<dim3(NWG), 256, 0, stream>>>(Qh, Kh, part);
    combine_kernel<<<dim3((BATCH * HW) / 64), 256, 0, stream>>>(part, out);
}

// Round 13
// 173.143 us; speedup vs baseline: 1.6705x; 1.6705x over previous
//
#include <hip/hip_runtime.h>
#include <stdint.h>

#define HW 9216
#define CDIM 128
#define WIDTH 96
#define BATCH 2
#define SPLITS 48           // 48 key-splits -> 48 partial streams
#define KSPLIT 192          // keys per split; LDS 48 KB -> 3 blocks/CU
#define NKG 6               // 192 / 32 keys per key-group
#define QTILE 128           // q-rows per block (4 waves x 32q)
#define NQT (HW / QTILE)    // 72 q-tiles
#define NWG (NQT * SPLITS * BATCH)   // 6912 blocks = 8 x 864

// log2(e)/(0.1*sqrt(128)): logits in log2 domain, e = exp2(w). |w| <= 1.276.
#define QSCALE 1.2753324954171245f

typedef _Float16 half8 __attribute__((ext_vector_type(8)));
typedef float f32x16 __attribute__((ext_vector_type(16)));
typedef uint32_t u32x4 __attribute__((ext_vector_type(4)));

// ---------------------------------------------------------------------------
// Kernel 1: L2-normalize over C, write fp16 [B][HW][C] (unchanged).
// ---------------------------------------------------------------------------
__global__ __launch_bounds__(256) void norm_kernel(const float* __restrict__ fL,
                                                   const float* __restrict__ fR,
                                                   _Float16* __restrict__ Qh,
                                                   _Float16* __restrict__ Kh)
{
    __shared__ float ssred[4][64];
    __shared__ _Float16 ot[64 * 130];   // +2 halves pad -> bank advance 1/row

    const float* src = (blockIdx.y == 0) ? fL : fR;
    _Float16* dst    = (blockIdx.y == 0) ? Qh : Kh;
    const float outScale = (blockIdx.y == 0) ? QSCALE : 1.0f;

    const int t = threadIdx.x;
    const int pos_l = t & 63, cg = t >> 6;            // 4 channel groups of 32
    const int pos0 = blockIdx.x * 64;                  // 64 | HW so no straddle
    const int b = pos0 / HW, pos_in = pos0 % HW + pos_l;

    const float* p = src + (size_t)b * CDIM * HW + pos_in;

    float v[32];
    float ss = 0.f;
    #pragma unroll
    for (int j = 0; j < 32; ++j) {
        v[j] = p[(size_t)(cg * 32 + j) * HW];
        ss += v[j] * v[j];
    }
    ssred[cg][pos_l] = ss;
    __syncthreads();
    float tot = ssred[0][pos_l] + ssred[1][pos_l] + ssred[2][pos_l] + ssred[3][pos_l];
    float scale = outScale / fmaxf(sqrtf(tot), 1e-6f);

    #pragma unroll
    for (int j = 0; j < 32; ++j)
        ot[pos_l * 130 + cg * 32 + j] = (_Float16)(v[j] * scale);
    __syncthreads();

    uint4* og = (uint4*)(dst + (size_t)(b * HW + pos0 % HW + 0) * CDIM);
    #pragma unroll
    for (int i = 0; i < 4; ++i) {
        int idx = i * 256 + t;            // 0..1023 dwordx4 slots
        int row = idx >> 4, chunk = idx & 15;
        og[idx] = *(const uint4*)&ot[row * 130 + chunk * 8];
    }
}

// ---------------------------------------------------------------------------
// Kernel 2: correlation + softmax-accumulate with PV-MFMA reduction,
// REGISTER-MINIMAL variant.
//   r12 proved the math (passed, absmax 0.125) but spilled ~950 MB: too much
//   live state at the (256,3) budget (dual QK chains + mutable Bv + 16-reg
//   EPI transients). This round, same math, minimal footprint:
//   - single QK chain, EPI immediately (ping-pong was +1.5us in r9)
//   - EPI as two independent half-batches (8 transient regs, each feeds its
//     PV MFMA at once)
//   - Bv immutable; col2 base = 0; y handled as ay = ysp*l + pv_col2 with a
//     constant dy8 (+1 on col2 lanes) added to a TRANSIENT copy for kg>=3
//   Live state ~125 regs < 170 cap.
//   Checks: WRITE_SIZE ~13.8 MB / FETCH ~11.6 MB (spill gone), VGPR 110-140.
//   If no-spill and attn still >=70us -> latency-structural floor; revert r9.
// ---------------------------------------------------------------------------
__global__ __launch_bounds__(256, 3) void attn_kernel(const _Float16* __restrict__ Qh,
                                                      const _Float16* __restrict__ Kh,
                                                      float4* __restrict__ part)
{
    __shared__ __align__(16) _Float16 Ks[KSPLIT * 128];   // 48 KB, staged once
    __shared__ float tr[4][3][32];                        // PV transpose, 1.5 KB

    const int wg0 = blockIdx.x;
    const int nid = (wg0 & 7) * (NWG / 8) + (wg0 >> 3);
    const int qt = nid % NQT;
    const int sb = nid / NQT;                  // 0..95
    const int split = sb % SPLITS;
    const int b = sb / SPLITS;

    const int t = threadIdx.x;
    const int lane = t & 63, wave = t >> 6;        // 4 waves
    const int lane31 = lane & 31, hi = lane >> 5;
    const int ln15 = lane & 15, qd = lane >> 4;

    const char* kp0 = (const char*)(Kh + (size_t)b * HW * CDIM) +
                      (size_t)(split * KSPLIT) * (CDIM * 2);

    // ---- stage the whole K-split: wave stages rows [wave*48, wave*48+48) ----
    {
        int voff4[4];
        #pragma unroll
        for (int i = 0; i < 4; ++i) {
            int r = wave * 48 + i * 4 + qd;
            voff4[i] = r * 256 + ((ln15 ^ (r & 15)) << 4) - i * 1024;
        }
        _Float16* db = &Ks[wave * (48 * 128)];
        #pragma unroll
        for (int i = 0; i < 12; ++i)
            __builtin_amdgcn_global_load_lds(
                (const __attribute__((address_space(1))) uint32_t*)(kp0 + voff4[i & 3] + i * 1024),
                (__attribute__((address_space(3))) uint32_t*)(db + i * 512),
                16, 0, 0);
    }

    // ---- Q fragments (B-operand of QK): col = lane31 = q-row, k = hi*8+j ----
    half8 qf[8];
    {
        const char* qb = (const char*)(Qh +
            ((size_t)(b * HW + qt * QTILE + wave * 32 + lane31)) * CDIM);
        #pragma unroll
        for (int kc = 0; kc < 8; ++kc)
            qf[kc] = *(const half8*)(qb + kc * 32 + hi * 16);
    }

    // K-frag (A-operand) LDS byte offsets: row = lane31, chunk (kc*2+hi)^ln15
    int rdoff[8];
    #pragma unroll
    for (int kc = 0; kc < 8; ++kc)
        rdoff[kc] = (lane31 << 8) + ((((kc << 1) | hi) ^ ln15) << 4);

    // ---- V fragments (B-operand of PV), IMMUTABLE: per phase ph, 16-key
    // half m. B[k=hi*8+j][col=lane31]: col0=1 -> l, col1=x=32ph+16m+k -> ax,
    // col2=0 (y via ay = ysp*l + pv_col2; dy8 adds 1 for kg>=3), else 0.
    half8 Bv[3][2];
    {
        const int col = lane31;
        const uint32_t onepk = 0x3C003C00u;
        #pragma unroll
        for (int ph = 0; ph < 3; ++ph)
            #pragma unroll
            for (int m = 0; m < 2; ++m) {
                u32x4 bb;
                #pragma unroll
                for (int jj = 0; jj < 4; ++jj) {
                    float x0 = (float)(32 * ph + m * 16 + hi * 8 + 2 * jj);
                    uint32_t xpk = __builtin_bit_cast(uint32_t,
                                       __builtin_amdgcn_cvt_pkrtz(x0, x0 + 1.f));
                    bb[jj] = (col == 0) ? onepk : (col == 1) ? xpk : 0u;
                }
                Bv[ph][m] = __builtin_bit_cast(half8, bb);
            }
    }
    const _Float16 dv = (lane31 == 2) ? (_Float16)1.0f : (_Float16)0.0f;
    const half8 dy8 = { dv, dv, dv, dv, dv, dv, dv, dv };

    f32x16 pv = (f32x16)0.f;   // D[row=q'][col]: col0=l, col1=ax, col2=ay-part
    float mxs = -1.0e30f;

    const char* ksb = (const char*)&Ks[0];

    __syncthreads();   // K fully staged

    #define CHAIN(ACC, KG)                                                       \
        {                                                                        \
            __builtin_amdgcn_s_setprio(1);                                       \
            _Pragma("unroll")                                                    \
            for (int kc = 0; kc < 8; ++kc) {                                     \
                half8 kf = *(const half8*)(ksb + (KG) * 8192 + rdoff[kc]);       \
                ACC = __builtin_amdgcn_mfma_f32_32x32x16_f16(                    \
                    kf, qf[kc], (kc == 0) ? (f32x16)0.f : ACC, 0, 0, 0);         \
            }                                                                    \
            __builtin_amdgcn_s_setprio(0);                                       \
        }

    // one 16-key half: exp2 + max + pack + cross-hi exchange + 1 PV MFMA.
    // (a-frag assembly pattern verified in r12 end-to-end.)
    #define EPIH(ACC, PH, M, PO, YB)                                             \
        {                                                                        \
            uint32_t ep[4], sw[4];                                               \
            _Pragma("unroll")                                                    \
            for (int p4 = 0; p4 < 4; ++p4) {                                     \
                float wx = ACC[2 * ((PO) + p4)], wy = ACC[2 * ((PO) + p4) + 1];  \
                mxs = fmaxf(mxs, fmaxf(wx, wy));                                 \
                ep[p4] = __builtin_bit_cast(uint32_t,                            \
                             __builtin_amdgcn_cvt_pkrtz(                         \
                                 __builtin_amdgcn_exp2f(wx),                     \
                                 __builtin_amdgcn_exp2f(wy)));                   \
            }                                                                    \
            _Pragma("unroll")                                                    \
            for (int p4 = 0; p4 < 4; ++p4)                                       \
                sw[p4] = (uint32_t)__shfl_xor((int)ep[p4], 32, 64);              \
            u32x4 a;                                                             \
            a[0] = hi ? sw[2] : ep[0]; a[1] = hi ? sw[3] : ep[1];                \
            a[2] = hi ? ep[2] : sw[0]; a[3] = hi ? ep[3] : sw[1];                \
            half8 bb = Bv[PH][M];                                                \
            if (YB) bb += dy8;                                                   \
            pv = __builtin_amdgcn_mfma_f32_32x32x16_f16(                         \
                     __builtin_bit_cast(half8, a), bb, pv, 0, 0, 0);             \
        }

    #define KGSTEP(KG)                                                           \
        {                                                                        \
            f32x16 acc;                                                          \
            CHAIN(acc, KG)                                                       \
            EPIH(acc, (KG) % 3, 0, 0, (KG) >= 3)                                 \
            EPIH(acc, (KG) % 3, 1, 4, (KG) >= 3)                                 \
        }

    KGSTEP(0) KGSTEP(1) KGSTEP(2) KGSTEP(3) KGSTEP(4) KGSTEP(5)
    #undef KGSTEP
    #undef EPIH
    #undef CHAIN

    // ---- extract: PV D row q' = (r&3)+8*(r>>2)+4*hi, col = lane31 ----
    if (lane31 < 3) {
        #pragma unroll
        for (int r = 0; r < 16; ++r) {
            int qp = (r & 3) + 8 * (r >> 2) + 4 * hi;
            tr[wave][lane31][qp] = pv[r];
        }
    }
    float mx = fmaxf(mxs, __shfl_xor(mxs, 32, 64));   // both hi key-halves
    __syncthreads();

    if (hi == 0) {
        const float ysp = (float)(split * 2);
        float l  = tr[wave][0][lane31];
        float ax = tr[wave][1][lane31];
        float ay = ysp * l + tr[wave][2][lane31];
        int row = qt * QTILE + wave * 32 + lane31;
        part[(size_t)split * (BATCH * HW) + b * HW + row] =
            make_float4(l, ax, ay, __builtin_amdgcn_exp2f(mx));
    }
}

// ---------------------------------------------------------------------------
// Kernel 3: combine 48 partials per query row — 288 blocks, LDS tree-reduce.
// ---------------------------------------------------------------------------
__global__ __launch_bounds__(256) void combine_kernel(const float4* __restrict__ part,
                                                      float* __restrict__ out)
{
    __shared__ float4 red[3][64];
    const int t = threadIdx.x;
    const int r = t & 63, g = t >> 6;            // row-in-block, split-group
    const int tid = blockIdx.x * 64 + r;         // 0 .. B*HW-1 (288 blocks)
    const int b = tid / HW, pos = tid % HW;

    float l = 0.f, ax = 0.f, ay = 0.f, mx = 0.f;
    #pragma unroll
    for (int s = 0; s < 12; ++s) {
        float4 v = part[(size_t)(g * 12 + s) * (BATCH * HW) + tid];
        l += v.x; ax += v.y; ay += v.z; mx = fmaxf(mx, v.w);
    }
    if (g > 0) red[g - 1][r] = make_float4(l, ax, ay, mx);
    __syncthreads();
    if (g == 0) {
        #pragma unroll
        for (int i = 0; i < 3; ++i) {
            float4 v = red[i][r];
            l += v.x; ax += v.y; ay += v.z; mx = fmaxf(mx, v.w);
        }
        float inv = 1.0f / l;
        int x = pos % WIDTH, y = pos / WIDTH;
        out[(size_t)b * 2 * HW + pos]                      = ax * inv - (float)x;
        out[(size_t)b * 2 * HW + HW + pos]                 = ay * inv - (float)y;
        out[(size_t)BATCH * 2 * HW + (size_t)b * HW + pos] = mx * inv;
    }
}

// ---------------------------------------------------------------------------
extern "C" void kernel_launch(void* const* d_in, const int* in_sizes, int n_in,
                              void* d_out, int out_size, void* d_ws, size_t ws_size,
                              hipStream_t stream)
{
    const float* fL = (const float*)d_in[0];
    const float* fR = (const float*)d_in[1];
    float* out = (float*)d_out;

    char* ws = (char*)d_ws;
    const size_t QH_BYTES = (size_t)BATCH * HW * CDIM * sizeof(_Float16);  // 4.72 MB
    _Float16* Qh  = (_Float16*)ws;
    _Float16* Kh  = (_Float16*)(ws + QH_BYTES);
    float4*   part = (float4*)(ws + 2 * QH_BYTES);                         // 14.16 MB

    norm_kernel<<<dim3((BATCH * HW) / 64, 2), 256, 0, stream>>>(fL, fR, Qh, Kh);
    attn_kernel<<<dim3(NWG), 256, 0, stream>>>(Qh, Kh, part);
    combine_kernel<<<dim3((BATCH * HW) / 64), 256, 0, stream>>>(part, out);
}